// Round 8
// baseline (341.663 us; speedup 1.0000x reference)
//
#include <hip/hip_runtime.h>
#include <math.h>

typedef unsigned short u16;
typedef u16   u16x8  __attribute__((ext_vector_type(8)));
typedef u16   u16x4  __attribute__((ext_vector_type(4)));
typedef __bf16 bf16x8 __attribute__((ext_vector_type(8)));
typedef float f32x4  __attribute__((ext_vector_type(4)));

// B=4 S=1024 E=768 H=8 HD=96 FF=3072
#define SZ_BSE   3145728
#define HEADSZ   98304
#define SCALING  0.10206207261596577f

__device__ __forceinline__ u16 f2bf(float f) {
  union { float f; unsigned u; } c; c.f = f;
  unsigned u = c.u;
  return (u16)((u + 0x7fffu + ((u >> 16) & 1u)) >> 16);
}
__device__ __forceinline__ float bf2f(u16 v) {
  union { unsigned u; float f; } c; c.u = ((unsigned)v) << 16; return c.f;
}

typedef const __attribute__((address_space(1))) unsigned int* gas1_t;
typedef __attribute__((address_space(3))) unsigned int* las3_t;
__device__ __forceinline__ void gload16(const void* g, void* l) {
  __builtin_amdgcn_global_load_lds((gas1_t)g, (las3_t)l, 16, 0, 0);
}

// ---------------- all weights fp32 -> bf16, one launch ----------------
struct CvtArgs {
  const float* src[6];
  u16* dst[6];
};
__global__ __launch_bounds__(256) void cvtall_k(CvtArgs a) {
  int bid = blockIdx.x;
  int which, base;
  if (bid < 2304)      { which = bid / 576; base = (bid - which * 576) * 1024; }
  else if (bid < 4608) { which = 4; base = (bid - 2304) * 1024; }
  else                 { which = 5; base = (bid - 4608) * 1024; }
  int i = base + threadIdx.x * 4;
  f32x4 v = *(const f32x4*)&a.src[which][i];
  u16x4 o; o[0]=f2bf(v[0]); o[1]=f2bf(v[1]); o[2]=f2bf(v[2]); o[3]=f2bf(v[3]);
  *(u16x4*)&a.dst[which][i] = o;
}

// ---------------- LayerNorm (row of 768) -> bf16 ----------------
__global__ __launch_bounds__(256) void ln_k(const float* __restrict__ x,
                                            const float* __restrict__ g,
                                            const float* __restrict__ b,
                                            u16* __restrict__ out) {
  const int row = blockIdx.x;
  const float* xr = x + (long)row * 768;
  const int t = threadIdx.x;
  float v0 = xr[t], v1 = xr[t + 256], v2 = xr[t + 512];
  float s = v0 + v1 + v2, ss = v0*v0 + v1*v1 + v2*v2;
  for (int o = 32; o > 0; o >>= 1) { s += __shfl_xor(s, o); ss += __shfl_xor(ss, o); }
  __shared__ float red[8];
  int w = t >> 6;
  if ((t & 63) == 0) { red[w] = s; red[w + 4] = ss; }
  __syncthreads();
  s  = red[0] + red[1] + red[2] + red[3];
  ss = red[4] + red[5] + red[6] + red[7];
  float mean = s * (1.0f / 768.0f);
  float var  = ss * (1.0f / 768.0f) - mean * mean;
  float rstd = rsqrtf(var + 1e-5f);
  u16* orow = out + (long)row * 768;
  orow[t]       = f2bf((v0 - mean) * rstd * g[t]       + b[t]);
  orow[t + 256] = f2bf((v1 - mean) * rstd * g[t + 256] + b[t + 256]);
  orow[t + 512] = f2bf((v2 - mean) * rstd * g[t + 512] + b[t + 512]);
}

// ---------------- split-K reduce: out = resid + bias + p0+p1+p2 ----------------
__global__ __launch_bounds__(256) void reduce_k(const float* __restrict__ p,
                                                const float* __restrict__ resid,
                                                const float* __restrict__ bias,
                                                float* __restrict__ out) {
  long i = ((long)blockIdx.x * 256 + threadIdx.x) * 4;
  f32x4 a = *(const f32x4*)&p[i];
  f32x4 b = *(const f32x4*)&p[3145728 + i];
  f32x4 c = *(const f32x4*)&p[6291456 + i];
  f32x4 r = *(const f32x4*)&resid[i];
  int cb = (int)(i % 768);
  f32x4 g = *(const f32x4*)&bias[cb];
  f32x4 o;
  o[0] = r[0] + g[0] + a[0] + b[0] + c[0];
  o[1] = r[1] + g[1] + a[1] + b[1] + c[1];
  o[2] = r[2] + g[2] + a[2] + b[2] + c[2];
  o[3] = r[3] + g[3] + a[3] + b[3] + c[3];
  *(f32x4*)&out[i] = o;
}

// ================= attention: 2 passes =================
// scores_k: e = exp(masked(QK^T)*scale) f32 -> probs region (raw), + rowsInv.
__global__ __launch_bounds__(512, 4)
void scores_k(const u16* __restrict__ qb, const u16* __restrict__ kb,
              const int* __restrict__ maskp, float* __restrict__ probs,
              float* __restrict__ rowsInv) {
  __shared__ float sSum[2][64];
  __shared__ u16 sFlag[1024];

  const int t = threadIdx.x;
  const int z = blockIdx.y;          // b*8+h
  const int r0 = blockIdx.x * 64;
  const int b = z >> 3;

  {
    const int* mp = maskp + b * 1024 + t * 2;
    int2 mv = *(const int2*)mp;
    sFlag[t * 2]     = (u16)(mv.x != 0);
    sFlag[t * 2 + 1] = (u16)(mv.y != 0);
  }
  __syncthreads();

  const int lane = t & 63;
  const int w = t >> 6;
  const int rs = w & 3, ch = w >> 2;
  const int wr0 = rs * 16;
  const int lr = lane & 15, lg = lane >> 4;
  const int cbase = ch * 512;

  const u16* qh = qb + (long)z * HEADSZ;
  const u16* kh = kb + (long)z * HEADSZ;
  float* ph = probs + (long)z * 1048576;

  bf16x8 qa[3];
  {
    const u16* qr = qh + (long)(r0 + wr0 + lr) * 96 + lg * 8;
#pragma unroll
    for (int kf = 0; kf < 3; ++kf) qa[kf] = *(const bf16x8*)(qr + kf * 32);
  }

  const float neg = -10000.0f * SCALING;
  float srun[4] = {0.f, 0.f, 0.f, 0.f};

  for (int c = 0; c < 8; ++c) {
    const int c0 = cbase + c * 64;
    f32x4 a4[4] = {};
#pragma unroll
    for (int ni = 0; ni < 4; ++ni) {
      const u16* kr = kh + (long)(c0 + ni * 16 + lr) * 96 + lg * 8;
#pragma unroll
      for (int kf = 0; kf < 3; ++kf)
        a4[ni] = __builtin_amdgcn_mfma_f32_16x16x32_bf16(
            qa[kf], *(const bf16x8*)(kr + kf * 32), a4[ni], 0, 0, 0);
    }
#pragma unroll
    for (int ni = 0; ni < 4; ++ni) {
      bool fm = sFlag[c0 + ni * 16 + lr] != 0;
      float* pp = ph + (long)(r0 + wr0 + lg * 4) * 1024 + c0 + ni * 16 + lr;
#pragma unroll
      for (int r = 0; r < 4; ++r) {
        float sv = fm ? neg : a4[ni][r] * SCALING;
        float e = __expf(sv);
        srun[r] += e;
        pp[r * 1024] = e;
      }
    }
  }

#pragma unroll
  for (int r = 0; r < 4; ++r) {
    float s = srun[r];
    s += __shfl_xor(s, 1);
    s += __shfl_xor(s, 2);
    s += __shfl_xor(s, 4);
    s += __shfl_xor(s, 8);
    if (lr == 0) sSum[ch][wr0 + lg * 4 + r] = s;
  }
  __syncthreads();
  if (ch == 0 && lr == 0) {
#pragma unroll
    for (int r = 0; r < 4; ++r) {
      float iv = 1.0f / (sSum[0][wr0 + lg * 4 + r] + sSum[1][wr0 + lg * 4 + r]);
      rowsInv[(long)z * 1024 + r0 + wr0 + lg * 4 + r] = iv;
    }
  }
}

// pv2_k: fused normalize+dist (probs written in place over e) + PV MFMA.
__global__ __launch_bounds__(512, 2)
void pv2_k(float* __restrict__ probs, const float* __restrict__ dist,
           const float* __restrict__ rowsInv, const u16* __restrict__ vT,
           u16* __restrict__ ctx) {
  __shared__ u16 sP[8 * 16 * 72];
  __shared__ float sX[4 * 64 * 24];

  const int t = threadIdx.x;
  const int z = blockIdx.y;
  const int r0 = blockIdx.x * 64;
  const int b = z >> 3, h = z & 7;
  const int lane = t & 63, w = t >> 6;
  const int rs = w & 3, ch = w >> 2;
  const int wr0 = rs * 16;
  const int lr = lane & 15, lg = lane >> 4;
  const int cbase = ch * 512;
  const int lrow = lane >> 2;
  const int cg = (lane & 3) * 16;
  u16* sPw = sP + w * (16 * 72);

  float* ph = probs + (long)z * 1048576;
  const float* dh = dist + (long)z * 1048576;
  const u16* vh = vT + (long)z * HEADSZ;
  const float iv = rowsInv[(long)z * 1024 + r0 + wr0 + lrow];

  f32x4 cacc[6] = {};
#pragma unroll
  for (int c = 0; c < 8; ++c) {
    const int c0 = cbase + c * 64;
    float* pp = ph + (long)(r0 + wr0 + lrow) * 1024 + c0 + cg;
    const float* dp = dh + (long)(r0 + wr0 + lrow) * 1024 + c0 + cg;
    f32x4 e0 = *(const f32x4*)pp;
    f32x4 e1 = *(const f32x4*)(pp + 4);
    f32x4 e2 = *(const f32x4*)(pp + 8);
    f32x4 e3 = *(const f32x4*)(pp + 12);
    f32x4 d0 = *(const f32x4*)dp;
    f32x4 d1 = *(const f32x4*)(dp + 4);
    f32x4 d2 = *(const f32x4*)(dp + 8);
    f32x4 d3 = *(const f32x4*)(dp + 12);
    f32x4 p0, p1, p2, p3;
#pragma unroll
    for (int j = 0; j < 4; ++j) {
      p0[j] = (e0[j] * iv + d0[j]) * 0.5f;
      p1[j] = (e1[j] * iv + d1[j]) * 0.5f;
      p2[j] = (e2[j] * iv + d2[j]) * 0.5f;
      p3[j] = (e3[j] * iv + d3[j]) * 0.5f;
    }
    *(f32x4*)pp        = p0;
    *(f32x4*)(pp + 4)  = p1;
    *(f32x4*)(pp + 8)  = p2;
    *(f32x4*)(pp + 12) = p3;
    u16x8 o0, o1;
#pragma unroll
    for (int j = 0; j < 4; ++j) {
      o0[j] = f2bf(p0[j]); o0[4 + j] = f2bf(p1[j]);
      o1[j] = f2bf(p2[j]); o1[4 + j] = f2bf(p3[j]);
    }
    *(u16x8*)&sPw[lrow * 72 + cg]     = o0;
    *(u16x8*)&sPw[lrow * 72 + cg + 8] = o1;

    // PV (wave-private sP tile; in-wave lgkm ordering)
#pragma unroll
    for (int ks = 0; ks < 2; ++ks) {
      bf16x8 pa = *(const bf16x8*)&sPw[lr * 72 + ks * 32 + lg * 8];
      const u16* vr = vh + (long)lr * 1024 + c0 + ks * 32 + lg * 8;
#pragma unroll
      for (int n2 = 0; n2 < 6; ++n2) {
        bf16x8 vb = *(const bf16x8*)(vr + (long)n2 * 16384);
        cacc[n2] = __builtin_amdgcn_mfma_f32_16x16x32_bf16(pa, vb, cacc[n2], 0, 0, 0);
      }
    }
  }

  __syncthreads();
  if (ch == 1) {
    float* xp = sX + ((rs * 64 + lane) * 24);
#pragma unroll
    for (int n2 = 0; n2 < 6; ++n2) *(f32x4*)&xp[n2 * 4] = cacc[n2];
  }
  __syncthreads();
  if (ch == 0) {
    const float* xp = sX + ((rs * 64 + lane) * 24);
    u16* cbp = ctx + (long)b * 786432 + h * 96;
#pragma unroll
    for (int n2 = 0; n2 < 6; ++n2) {
      f32x4 xv = *(const f32x4*)&xp[n2 * 4];
      int d = n2 * 16 + lr;
#pragma unroll
      for (int r = 0; r < 4; ++r)
        cbp[(long)(r0 + wr0 + lg * 4 + r) * 768 + d] = f2bf(cacc[n2][r] + xv[r]);
    }
  }
}

// ---------------- MFMA GEMM, m97 structure: global_load_lds staging ----------------
enum { EPI_QKV = 0, EPI_GELU = 1, EPI_PARTIAL = 2 };

template <int EPI>
__global__ __launch_bounds__(256, 2)
void gemm_k(const u16* __restrict__ A, int lda,
            const u16* __restrict__ W, int ldw,
            void* __restrict__ Cv, long sCz, int ldc,
            const float* __restrict__ bias,
            u16* __restrict__ vt,
            int N, int K, int kchunks) {
  __shared__ u16 sA[4096]; // [128][32] linear
  __shared__ u16 sB[4096];

  const int t  = threadIdx.x;
  const int kc = blockIdx.z;
  const int klen = K / kchunks;
  const int kbeg = kc * klen, kend = kbeg + klen;
  const int m0 = blockIdx.x * 128;
  const int n0 = blockIdx.y * 128;

  const int r0 = t >> 2;
  const int c0 = (t & 3) << 3;
  char* lA = (char*)sA + ((t >> 6) << 10);
  char* lB = (char*)sB + ((t >> 6) << 10);

  int bn0 = n0 + r0;      if (bn0 > N - 1) bn0 = N - 1;
  int bn1 = n0 + 64 + r0; if (bn1 > N - 1) bn1 = N - 1;
  const u16* gB0 = W + (long)bn0 * ldw + c0;
  const u16* gB1 = W + (long)bn1 * ldw + c0;
  const u16* gA0 = A + (long)(m0 + r0) * lda + c0;
  const u16* gA1 = gA0 + 64 * lda;

  const int lane = t & 63;
  const int w  = t >> 6;
  const int wm = (w >> 1) * 64, wn = (w & 1) * 64;
  const int lr = lane & 15, lg = lane >> 4;

  f32x4 acc[4][4] = {};

  for (int k0 = kbeg; k0 < kend; k0 += 32) {
    gload16(gA0 + k0, lA);
    gload16(gA1 + k0, lA + 4096);
    gload16(gB0 + k0, lB);
    gload16(gB1 + k0, lB + 4096);
    __syncthreads();

    bf16x8 aF[4], bF[4];
#pragma unroll
    for (int mi = 0; mi < 4; ++mi)
      aF[mi] = *(const bf16x8*)&sA[(wm + mi * 16 + lr) * 32 + lg * 8];
#pragma unroll
    for (int ni = 0; ni < 4; ++ni)
      bF[ni] = *(const bf16x8*)&sB[(wn + ni * 16 + lr) * 32 + lg * 8];
#pragma unroll
    for (int mi = 0; mi < 4; ++mi)
#pragma unroll
      for (int ni = 0; ni < 4; ++ni)
        acc[mi][ni] = __builtin_amdgcn_mfma_f32_16x16x32_bf16(aF[mi], bF[ni], acc[mi][ni], 0, 0, 0);
    __syncthreads();
  }

  long coff = (EPI == EPI_PARTIAL) ? (long)kc * sCz : 0;

#pragma unroll
  for (int mi = 0; mi < 4; ++mi) {
#pragma unroll
    for (int ni = 0; ni < 4; ++ni) {
      int gc = n0 + wn + ni * 16 + lr;
      if (gc >= N) continue;
      int gr0 = m0 + wm + mi * 16 + lg * 4;
#pragma unroll
      for (int r = 0; r < 4; ++r) {
        float vv = acc[mi][ni][r];
        if (EPI == EPI_QKV) {
          vv += bias[gc];
          if (gc >= 1536) {
            // V -> vT[b*8+h][d][s] under RESHAPE semantics:
            // flat-in-batch f = sr*768 + c; h = f/98304 = sr>>7;
            // s = (f%98304)/96 = (sr&127)*8 + c/96; d = c%96.
            int c = gc - 1536;
            int row = gr0 + r, bb = row >> 10, sr = row & 1023;
            int hh = sr >> 7;
            int cd = c / 96;
            int ss = ((sr & 127) << 3) + cd;
            int dd = c - cd * 96;
            vt[(long)(bb * 8 + hh) * HEADSZ + (long)dd * 1024 + ss] = f2bf(vv);
          } else {
            int wsel = gc >= 768 ? 1 : 0;
            int c = gc - wsel * 768;
            ((u16*)Cv)[(long)wsel * 3145728 + (long)(gr0 + r) * 768 + c] = f2bf(vv);
          }
        } else if (EPI == EPI_GELU) {
          vv += bias[gc];
          vv = 0.5f * vv * (1.0f + erff(vv * 0.70710678118654752f));
          ((u16*)Cv)[coff + (long)(gr0 + r) * ldc + gc] = f2bf(vv);
        } else {
          ((float*)Cv)[coff + (long)(gr0 + r) * ldc + gc] = vv;
        }
      }
    }
  }
}

extern "C" void kernel_launch(void* const* d_in, const int* in_sizes, int n_in,
                              void* d_out, int out_size, void* d_ws, size_t ws_size,
                              hipStream_t stream) {
  (void)in_sizes; (void)n_in; (void)out_size; (void)ws_size;
  const float* x    = (const float*)d_in[0];
  const float* dist = (const float*)d_in[1];
  const int*   mask = (const int*)d_in[2];
  const float* Wq = (const float*)d_in[3];  const float* bq  = (const float*)d_in[4];
  const float* Wk = (const float*)d_in[5];  const float* bk  = (const float*)d_in[6];
  const float* Wv = (const float*)d_in[7];  const float* bv  = (const float*)d_in[8];
  const float* Wo = (const float*)d_in[9];  const float* bo  = (const float*)d_in[10];
  const float* g1 = (const float*)d_in[11]; const float* b1n = (const float*)d_in[12];
  const float* W1 = (const float*)d_in[13]; const float* b1f = (const float*)d_in[14];
  const float* W2 = (const float*)d_in[15]; const float* b2f = (const float*)d_in[16];
  const float* g2 = (const float*)d_in[17]; const float* b2n = (const float*)d_in[18];

  char* ws = (char*)d_ws;
  u16*   h    = (u16*)(ws + 0);          // LN1 out; later reused as ctx
  u16*   ctx  = (u16*)(ws + 0);
  u16*   qk   = (u16*)(ws + 6291456);    // q,k contiguous
  u16*   q    = qk;
  u16*   k    = (u16*)(ws + 12582912);
  u16*   vT   = (u16*)(ws + 25165824);
  float* part = (float*)(ws + 6291456);  // 3 planes (reuses dead q/k/vT)
  u16*   h2   = (u16*)(ws + 31457280);
  u16*   ffn1 = (u16*)(ws + 44040192);
  float* x1   = (float*)(ws + 69206016);
  u16*   wqkvb= (u16*)(ws + 81788928);
  u16*   wob  = (u16*)(ws + 85327872);
  u16*   w1b  = (u16*)(ws + 86507520);
  u16*   w2b  = (u16*)(ws + 91226112);
  float* bqkv = (float*)(ws + 95944704);
  float* rowsInv = (float*)(ws + 95953920); // 32*1024 f32 = 128KB

  float* outp   = (float*)d_out;
  float* probs  = outp + SZ_BSE;

  CvtArgs ca;
  ca.src[0] = Wq; ca.src[1] = Wk; ca.src[2] = Wv;
  ca.src[3] = Wo; ca.src[4] = W1; ca.src[5] = W2;
  ca.dst[0] = wqkvb; ca.dst[1] = wqkvb + 589824; ca.dst[2] = wqkvb + 1179648;
  ca.dst[3] = wob;   ca.dst[4] = w1b;            ca.dst[5] = w2b;
  cvtall_k<<<6912, 256, 0, stream>>>(ca);
  hipMemcpyAsync(bqkv,        bq, 3072, hipMemcpyDeviceToDevice, stream);
  hipMemcpyAsync(bqkv + 768,  bk, 3072, hipMemcpyDeviceToDevice, stream);
  hipMemcpyAsync(bqkv + 1536, bv, 3072, hipMemcpyDeviceToDevice, stream);

  ln_k<<<4096, 256, 0, stream>>>(x, g1, b1n, h);

  // fused QKV; V written directly transposed (reshape-correct) to vT
  gemm_k<EPI_QKV><<<dim3(32, 18, 1), 256, 0, stream>>>(
      h, 768, wqkvb, 768, qk, 0, 768, bqkv, vT, 2304, 768, 1);

  // attention: e f32 + rowsInv, then fused normalize+dist+PV
  scores_k<<<dim3(16, 32), 512, 0, stream>>>(q, k, mask, probs, rowsInv);
  pv2_k<<<dim3(16, 32), 512, 0, stream>>>(probs, dist, rowsInv, vT, ctx);

  gemm_k<EPI_PARTIAL><<<dim3(32, 6, 3), 256, 0, stream>>>(
      ctx, 768, wob, 768, part, 3145728, 768, nullptr, nullptr, 768, 768, 3);
  reduce_k<<<3072, 256, 0, stream>>>(part, x, bo, x1);

  ln_k<<<4096, 256, 0, stream>>>(x1, g2, b2n, h2);

  gemm_k<EPI_GELU><<<dim3(32, 24, 1), 256, 0, stream>>>(
      h2, 768, w1b, 768, ffn1, 0, 3072, b1f, nullptr, 3072, 768, 1);

  gemm_k<EPI_PARTIAL><<<dim3(32, 6, 3), 256, 0, stream>>>(
      ffn1, 3072, w2b, 3072, part, 3145728, 768, nullptr, nullptr, 768, 3072, 3);
  reduce_k<<<3072, 256, 0, stream>>>(part, x1, b2f, outp);
}

// Round 9
// 329.282 us; speedup vs baseline: 1.0376x; 1.0376x over previous
//
#include <hip/hip_runtime.h>
#include <math.h>

typedef unsigned short u16;
typedef u16   u16x8  __attribute__((ext_vector_type(8)));
typedef u16   u16x4  __attribute__((ext_vector_type(4)));
typedef __bf16 bf16x8 __attribute__((ext_vector_type(8)));
typedef float f32x4  __attribute__((ext_vector_type(4)));

// B=4 S=1024 E=768 H=8 HD=96 FF=3072
#define SZ_BSE   3145728
#define HEADSZ   98304
#define SCALING  0.10206207261596577f

__device__ __forceinline__ u16 f2bf(float f) {
  union { float f; unsigned u; } c; c.f = f;
  unsigned u = c.u;
  return (u16)((u + 0x7fffu + ((u >> 16) & 1u)) >> 16);
}
__device__ __forceinline__ float bf2f(u16 v) {
  union { unsigned u; float f; } c; c.u = ((unsigned)v) << 16; return c.f;
}

typedef const __attribute__((address_space(1))) unsigned int* gas1_t;
typedef __attribute__((address_space(3))) unsigned int* las3_t;
__device__ __forceinline__ void gload16(const void* g, void* l) {
  __builtin_amdgcn_global_load_lds((gas1_t)g, (las3_t)l, 16, 0, 0);
}

// ---------------- all weights fp32 -> bf16, one launch ----------------
struct CvtArgs {
  const float* src[6];
  u16* dst[6];
};
__global__ __launch_bounds__(256) void cvtall_k(CvtArgs a) {
  int bid = blockIdx.x;
  int which, base;
  if (bid < 2304)      { which = bid / 576; base = (bid - which * 576) * 1024; }
  else if (bid < 4608) { which = 4; base = (bid - 2304) * 1024; }
  else                 { which = 5; base = (bid - 4608) * 1024; }
  int i = base + threadIdx.x * 4;
  f32x4 v = *(const f32x4*)&a.src[which][i];
  u16x4 o; o[0]=f2bf(v[0]); o[1]=f2bf(v[1]); o[2]=f2bf(v[2]); o[3]=f2bf(v[3]);
  *(u16x4*)&a.dst[which][i] = o;
}

// ---------------- LayerNorm (row of 768) -> bf16 ----------------
__global__ __launch_bounds__(256) void ln_k(const float* __restrict__ x,
                                            const float* __restrict__ g,
                                            const float* __restrict__ b,
                                            u16* __restrict__ out) {
  const int row = blockIdx.x;
  const float* xr = x + (long)row * 768;
  const int t = threadIdx.x;
  float v0 = xr[t], v1 = xr[t + 256], v2 = xr[t + 512];
  float s = v0 + v1 + v2, ss = v0*v0 + v1*v1 + v2*v2;
  for (int o = 32; o > 0; o >>= 1) { s += __shfl_xor(s, o); ss += __shfl_xor(ss, o); }
  __shared__ float red[8];
  int w = t >> 6;
  if ((t & 63) == 0) { red[w] = s; red[w + 4] = ss; }
  __syncthreads();
  s  = red[0] + red[1] + red[2] + red[3];
  ss = red[4] + red[5] + red[6] + red[7];
  float mean = s * (1.0f / 768.0f);
  float var  = ss * (1.0f / 768.0f) - mean * mean;
  float rstd = rsqrtf(var + 1e-5f);
  u16* orow = out + (long)row * 768;
  orow[t]       = f2bf((v0 - mean) * rstd * g[t]       + b[t]);
  orow[t + 256] = f2bf((v1 - mean) * rstd * g[t + 256] + b[t + 256]);
  orow[t + 512] = f2bf((v2 - mean) * rstd * g[t + 512] + b[t + 512]);
}

// ---------------- split-K reduce: out = resid + bias + p0+p1+p2 ----------------
__global__ __launch_bounds__(256) void reduce_k(const float* __restrict__ p,
                                                const float* __restrict__ resid,
                                                const float* __restrict__ bias,
                                                float* __restrict__ out) {
  long i = ((long)blockIdx.x * 256 + threadIdx.x) * 4;
  f32x4 a = *(const f32x4*)&p[i];
  f32x4 b = *(const f32x4*)&p[3145728 + i];
  f32x4 c = *(const f32x4*)&p[6291456 + i];
  f32x4 r = *(const f32x4*)&resid[i];
  int cb = (int)(i % 768);
  f32x4 g = *(const f32x4*)&bias[cb];
  f32x4 o;
  o[0] = r[0] + g[0] + a[0] + b[0] + c[0];
  o[1] = r[1] + g[1] + a[1] + b[1] + c[1];
  o[2] = r[2] + g[2] + a[2] + b[2] + c[2];
  o[3] = r[3] + g[3] + a[3] + b[3] + c[3];
  *(f32x4*)&out[i] = o;
}

// ================= attention: 3 roofline-separated stages =================
// scores_k: e = exp(masked(QK^T)*scale) -> bf16 in UPPER HALF of each probs row
//           (f32 row bytes [0,4096); e bytes [2048,4096)), + rowsInv.
__global__ __launch_bounds__(512, 4)
void scores_k(const u16* __restrict__ qb, const u16* __restrict__ kb,
              const int* __restrict__ maskp, float* __restrict__ probs,
              float* __restrict__ rowsInv) {
  __shared__ u16 sP[8 * 16 * 72];
  __shared__ float sSum[2][64];
  __shared__ u16 sFlag[1024];

  const int t = threadIdx.x;
  const int z = blockIdx.y;          // b*8+h
  const int r0 = blockIdx.x * 64;
  const int b = z >> 3;

  {
    const int* mp = maskp + b * 1024 + t * 2;
    int2 mv = *(const int2*)mp;
    sFlag[t * 2]     = (u16)(mv.x != 0);
    sFlag[t * 2 + 1] = (u16)(mv.y != 0);
  }
  __syncthreads();

  const int lane = t & 63;
  const int w = t >> 6;
  const int rs = w & 3, ch = w >> 2;
  const int wr0 = rs * 16;
  const int lr = lane & 15, lg = lane >> 4;
  const int cbase = ch * 512;
  u16* sPw = sP + w * (16 * 72);
  const int lrow = lane >> 2;
  const int cg = (lane & 3) * 16;

  const u16* qh = qb + (long)z * HEADSZ;
  const u16* kh = kb + (long)z * HEADSZ;
  u16* eb = (u16*)probs + (long)z * 2097152; // head base as u16 (2048 u16/row)

  bf16x8 qa[3];
  {
    const u16* qr = qh + (long)(r0 + wr0 + lr) * 96 + lg * 8;
#pragma unroll
    for (int kf = 0; kf < 3; ++kf) qa[kf] = *(const bf16x8*)(qr + kf * 32);
  }

  const float neg = -10000.0f * SCALING;
  float srun[4] = {0.f, 0.f, 0.f, 0.f};

  for (int c = 0; c < 8; ++c) {
    const int c0 = cbase + c * 64;
    f32x4 a4[4] = {};
#pragma unroll
    for (int ni = 0; ni < 4; ++ni) {
      const u16* kr = kh + (long)(c0 + ni * 16 + lr) * 96 + lg * 8;
#pragma unroll
      for (int kf = 0; kf < 3; ++kf)
        a4[ni] = __builtin_amdgcn_mfma_f32_16x16x32_bf16(
            qa[kf], *(const bf16x8*)(kr + kf * 32), a4[ni], 0, 0, 0);
    }
#pragma unroll
    for (int ni = 0; ni < 4; ++ni) {
      bool fm = sFlag[c0 + ni * 16 + lr] != 0;
#pragma unroll
      for (int r = 0; r < 4; ++r) {
        float sv = fm ? neg : a4[ni][r] * SCALING;
        float e = __expf(sv);
        srun[r] += e;
        sPw[(lg * 4 + r) * 72 + ni * 16 + lr] = f2bf(e);
      }
    }
    // coalesced e store (wave-private tile; in-wave lgkm ordering)
    u16x8 e0 = *(const u16x8*)&sPw[lrow * 72 + cg];
    u16x8 e1 = *(const u16x8*)&sPw[lrow * 72 + cg + 8];
    u16* ep = eb + (long)(r0 + wr0 + lrow) * 2048 + 1024 + c0 + cg;
    *(u16x8*)ep       = e0;
    *(u16x8*)(ep + 8) = e1;
  }

#pragma unroll
  for (int r = 0; r < 4; ++r) {
    float s = srun[r];
    s += __shfl_xor(s, 1);
    s += __shfl_xor(s, 2);
    s += __shfl_xor(s, 4);
    s += __shfl_xor(s, 8);
    if (lr == 0) sSum[ch][wr0 + lg * 4 + r] = s;
  }
  __syncthreads();
  if (ch == 0 && lr == 0) {
#pragma unroll
    for (int r = 0; r < 4; ++r) {
      float iv = 1.0f / (sSum[0][wr0 + lg * 4 + r] + sSum[1][wr0 + lg * 4 + r]);
      rowsInv[(long)z * 1024 + r0 + wr0 + lg * 4 + r] = iv;
    }
  }
}

// probs_k: streaming probs = (e*inv + dist)*0.5 in place over each row.
// 4 rows per block (wave w = row w); one barrier between e/dist loads and stores.
__global__ __launch_bounds__(256)
void probs_k(float* __restrict__ probs, const float* __restrict__ dist,
             const float* __restrict__ rowsInv) {
  const long gidx = (long)blockIdx.x * 4 + (threadIdx.x >> 6); // global row
  const int l16 = (threadIdx.x & 63) * 16;                     // col of 16-f32 slice
  float* pr = probs + gidx * 1024 + l16;
  const u16* er = (const u16*)(probs + gidx * 1024) + 1024 + l16;
  const float* dr = dist + gidx * 1024 + l16;
  const float iv = rowsInv[gidx];

  u16x8 e0 = *(const u16x8*)er;
  u16x8 e1 = *(const u16x8*)(er + 8);
  f32x4 d0 = *(const f32x4*)dr;
  f32x4 d1 = *(const f32x4*)(dr + 4);
  f32x4 d2 = *(const f32x4*)(dr + 8);
  f32x4 d3 = *(const f32x4*)(dr + 12);
  __syncthreads(); // all e reads in block done before any overwrite
  f32x4 o0, o1, o2, o3;
#pragma unroll
  for (int j = 0; j < 4; ++j) {
    o0[j] = (bf2f(e0[j])     * iv + d0[j]) * 0.5f;
    o1[j] = (bf2f(e0[4 + j]) * iv + d1[j]) * 0.5f;
    o2[j] = (bf2f(e1[j])     * iv + d2[j]) * 0.5f;
    o3[j] = (bf2f(e1[4 + j]) * iv + d3[j]) * 0.5f;
  }
  *(f32x4*)pr        = o0;
  *(f32x4*)(pr + 4)  = o1;
  *(f32x4*)(pr + 8)  = o2;
  *(f32x4*)(pr + 12) = o3;
}

// pv_k: ctx = probs(f32) @ V per head; 8 waves = 4 row-slices x 2 K-halves.
// No LDS in main loop; chunks independent.
__global__ __launch_bounds__(512, 4)
void pv_k(const float* __restrict__ probs, const u16* __restrict__ vT,
          u16* __restrict__ ctx) {
  __shared__ float sX[4 * 64 * 24];
  const int t = threadIdx.x;
  const int z = blockIdx.y;
  const int r0 = blockIdx.x * 64;
  const int b = z >> 3, h = z & 7;
  const int lane = t & 63, w = t >> 6;
  const int rs = w & 3, kh = w >> 2;
  const int wr0 = rs * 16;
  const int lr = lane & 15, lg = lane >> 4;

  const float* ph = probs + (long)z * 1048576 + (long)(r0 + wr0 + lr) * 1024 + lg * 8;
  const u16* vh = vT + (long)z * HEADSZ;
  const int cb = kh * 512;

  f32x4 cacc[6] = {};
#pragma unroll
  for (int c = 0; c < 8; ++c) {
    const int c0 = cb + c * 64;
    const float* pp = ph + c0;
    f32x4 p0 = *(const f32x4*)pp;
    f32x4 p1 = *(const f32x4*)(pp + 4);
    f32x4 p2 = *(const f32x4*)(pp + 32);
    f32x4 p3 = *(const f32x4*)(pp + 36);
    u16x8 w0, w1;
#pragma unroll
    for (int j = 0; j < 4; ++j) {
      w0[j] = f2bf(p0[j]); w0[4 + j] = f2bf(p1[j]);
      w1[j] = f2bf(p2[j]); w1[4 + j] = f2bf(p3[j]);
    }
    bf16x8 pa0 = *(bf16x8*)&w0;
    bf16x8 pa1 = *(bf16x8*)&w1;
    const u16* vr0 = vh + (long)lr * 1024 + c0 + lg * 8;
#pragma unroll
    for (int n2 = 0; n2 < 6; ++n2) {
      bf16x8 vb = *(const bf16x8*)(vr0 + (long)n2 * 16384);
      cacc[n2] = __builtin_amdgcn_mfma_f32_16x16x32_bf16(pa0, vb, cacc[n2], 0, 0, 0);
    }
#pragma unroll
    for (int n2 = 0; n2 < 6; ++n2) {
      bf16x8 vb = *(const bf16x8*)(vr0 + 32 + (long)n2 * 16384);
      cacc[n2] = __builtin_amdgcn_mfma_f32_16x16x32_bf16(pa1, vb, cacc[n2], 0, 0, 0);
    }
  }

  __syncthreads();
  if (kh == 1) {
    float* xp = sX + ((rs * 64 + lane) * 24);
#pragma unroll
    for (int n2 = 0; n2 < 6; ++n2) *(f32x4*)&xp[n2 * 4] = cacc[n2];
  }
  __syncthreads();
  if (kh == 0) {
    const float* xp = sX + ((rs * 64 + lane) * 24);
    u16* cbp = ctx + (long)b * 786432 + h * 96;
#pragma unroll
    for (int n2 = 0; n2 < 6; ++n2) {
      f32x4 xv = *(const f32x4*)&xp[n2 * 4];
      int d = n2 * 16 + lr;
#pragma unroll
      for (int r = 0; r < 4; ++r)
        cbp[(long)(r0 + wr0 + lg * 4 + r) * 768 + d] = f2bf(cacc[n2][r] + xv[r]);
    }
  }
}

// ---------------- MFMA GEMM, m97 structure, BK=64 (two 32-col LDS tiles) ----------------
enum { EPI_QKV = 0, EPI_GELU = 1, EPI_PARTIAL = 2 };

template <int EPI>
__global__ __launch_bounds__(256, 2)
void gemm_k(const u16* __restrict__ A, int lda,
            const u16* __restrict__ W, int ldw,
            void* __restrict__ Cv, long sCz, int ldc,
            const float* __restrict__ bias,
            u16* __restrict__ vt,
            int N, int K, int kchunks) {
  __shared__ u16 sA[8192]; // two [128][32] tiles: cols 0-31 @0, cols 32-63 @4096
  __shared__ u16 sB[8192];

  const int t  = threadIdx.x;
  const int kc = blockIdx.z;
  const int klen = K / kchunks;
  const int kbeg = kc * klen, kend = kbeg + klen;
  const int m0 = blockIdx.x * 128;
  const int n0 = blockIdx.y * 128;

  const int r0 = t >> 2;            // row within 64-row half
  const int c0 = (t & 3) << 3;      // col offset 0,8,16,24
  char* lA = (char*)sA + ((t >> 6) << 10); // wave-uniform LDS base
  char* lB = (char*)sB + ((t >> 6) << 10);

  const u16* gB0 = W + (long)(n0 + r0) * ldw + c0;
  const u16* gB1 = gB0 + 64 * ldw;
  const u16* gA0 = A + (long)(m0 + r0) * lda + c0;
  const u16* gA1 = gA0 + 64 * lda;

  const int lane = t & 63;
  const int w  = t >> 6;
  const int wm = (w >> 1) * 64, wn = (w & 1) * 64;
  const int lr = lane & 15, lg = lane >> 4;

  f32x4 acc[4][4] = {};

  for (int k0 = kbeg; k0 < kend; k0 += 64) {
    gload16(gA0 + k0,      lA);
    gload16(gA1 + k0,      lA + 4096);
    gload16(gA0 + k0 + 32, lA + 8192);
    gload16(gA1 + k0 + 32, lA + 12288);
    gload16(gB0 + k0,      lB);
    gload16(gB1 + k0,      lB + 4096);
    gload16(gB0 + k0 + 32, lB + 8192);
    gload16(gB1 + k0 + 32, lB + 12288);
    __syncthreads();

#pragma unroll
    for (int kk = 0; kk < 2; ++kk) {
      bf16x8 aF[4], bF[4];
#pragma unroll
      for (int mi = 0; mi < 4; ++mi)
        aF[mi] = *(const bf16x8*)&sA[kk * 4096 + (wm + mi * 16 + lr) * 32 + lg * 8];
#pragma unroll
      for (int ni = 0; ni < 4; ++ni)
        bF[ni] = *(const bf16x8*)&sB[kk * 4096 + (wn + ni * 16 + lr) * 32 + lg * 8];
#pragma unroll
      for (int mi = 0; mi < 4; ++mi)
#pragma unroll
        for (int ni = 0; ni < 4; ++ni)
          acc[mi][ni] = __builtin_amdgcn_mfma_f32_16x16x32_bf16(aF[mi], bF[ni], acc[mi][ni], 0, 0, 0);
    }
    __syncthreads();
  }

  long coff = (EPI == EPI_PARTIAL) ? (long)kc * sCz : 0;

#pragma unroll
  for (int mi = 0; mi < 4; ++mi) {
#pragma unroll
    for (int ni = 0; ni < 4; ++ni) {
      int gc = n0 + wn + ni * 16 + lr;
      int gr0 = m0 + wm + mi * 16 + lg * 4;
#pragma unroll
      for (int r = 0; r < 4; ++r) {
        float vv = acc[mi][ni][r];
        if (EPI == EPI_QKV) {
          vv += bias[gc];
          if (gc >= 1536) {
            // V -> vT[b*8+h][d][s] under RESHAPE semantics:
            // h = sr>>7; s = (sr&127)*8 + c/96; d = c%96.
            int c = gc - 1536;
            int row = gr0 + r, bb = row >> 10, sr = row & 1023;
            int hh = sr >> 7;
            int cd = c / 96;
            int ss = ((sr & 127) << 3) + cd;
            int dd = c - cd * 96;
            vt[(long)(bb * 8 + hh) * HEADSZ + (long)dd * 1024 + ss] = f2bf(vv);
          } else {
            int wsel = gc >= 768 ? 1 : 0;
            int c = gc - wsel * 768;
            ((u16*)Cv)[(long)wsel * 3145728 + (long)(gr0 + r) * 768 + c] = f2bf(vv);
          }
        } else if (EPI == EPI_GELU) {
          vv += bias[gc];
          vv = 0.5f * vv * (1.0f + erff(vv * 0.70710678118654752f));
          ((u16*)Cv)[coff + (long)(gr0 + r) * ldc + gc] = f2bf(vv);
        } else {
          ((float*)Cv)[coff + (long)(gr0 + r) * ldc + gc] = vv;
        }
      }
    }
  }
}

extern "C" void kernel_launch(void* const* d_in, const int* in_sizes, int n_in,
                              void* d_out, int out_size, void* d_ws, size_t ws_size,
                              hipStream_t stream) {
  (void)in_sizes; (void)n_in; (void)out_size; (void)ws_size;
  const float* x    = (const float*)d_in[0];
  const float* dist = (const float*)d_in[1];
  const int*   mask = (const int*)d_in[2];
  const float* Wq = (const float*)d_in[3];  const float* bq  = (const float*)d_in[4];
  const float* Wk = (const float*)d_in[5];  const float* bk  = (const float*)d_in[6];
  const float* Wv = (const float*)d_in[7];  const float* bv  = (const float*)d_in[8];
  const float* Wo = (const float*)d_in[9];  const float* bo  = (const float*)d_in[10];
  const float* g1 = (const float*)d_in[11]; const float* b1n = (const float*)d_in[12];
  const float* W1 = (const float*)d_in[13]; const float* b1f = (const float*)d_in[14];
  const float* W2 = (const float*)d_in[15]; const float* b2f = (const float*)d_in[16];
  const float* g2 = (const float*)d_in[17]; const float* b2n = (const float*)d_in[18];

  char* ws = (char*)d_ws;
  u16*   h    = (u16*)(ws + 0);          // LN1 out; later reused as ctx
  u16*   ctx  = (u16*)(ws + 0);
  u16*   qk   = (u16*)(ws + 6291456);    // q,k contiguous
  u16*   q    = qk;
  u16*   k    = (u16*)(ws + 12582912);
  u16*   vT   = (u16*)(ws + 25165824);
  float* part = (float*)(ws + 6291456);  // 3 planes (reuses dead q/k/vT)
  u16*   h2   = (u16*)(ws + 31457280);
  u16*   ffn1 = (u16*)(ws + 44040192);
  float* x1   = (float*)(ws + 69206016);
  u16*   wqkvb= (u16*)(ws + 81788928);
  u16*   wob  = (u16*)(ws + 85327872);
  u16*   w1b  = (u16*)(ws + 86507520);
  u16*   w2b  = (u16*)(ws + 91226112);
  float* bqkv = (float*)(ws + 95944704);
  float* rowsInv = (float*)(ws + 95953920); // 32*1024 f32 = 128KB

  float* outp   = (float*)d_out;
  float* probs  = outp + SZ_BSE;

  CvtArgs ca;
  ca.src[0] = Wq; ca.src[1] = Wk; ca.src[2] = Wv;
  ca.src[3] = Wo; ca.src[4] = W1; ca.src[5] = W2;
  ca.dst[0] = wqkvb; ca.dst[1] = wqkvb + 589824; ca.dst[2] = wqkvb + 1179648;
  ca.dst[3] = wob;   ca.dst[4] = w1b;            ca.dst[5] = w2b;
  cvtall_k<<<6912, 256, 0, stream>>>(ca);
  hipMemcpyAsync(bqkv,        bq, 3072, hipMemcpyDeviceToDevice, stream);
  hipMemcpyAsync(bqkv + 768,  bk, 3072, hipMemcpyDeviceToDevice, stream);
  hipMemcpyAsync(bqkv + 1536, bv, 3072, hipMemcpyDeviceToDevice, stream);

  ln_k<<<4096, 256, 0, stream>>>(x, g1, b1n, h);

  // fused QKV; V written directly transposed (reshape-correct) to vT
  gemm_k<EPI_QKV><<<dim3(32, 18, 1), 256, 0, stream>>>(
      h, 768, wqkvb, 768, qk, 0, 768, bqkv, vT, 2304, 768, 1);

  // attention middle, 3 roofline-separated stages
  scores_k<<<dim3(16, 32), 512, 0, stream>>>(q, k, mask, probs, rowsInv);
  probs_k<<<8192, 256, 0, stream>>>(probs, dist, rowsInv);
  pv_k<<<dim3(16, 32), 512, 0, stream>>>(probs, vT, ctx);

  gemm_k<EPI_PARTIAL><<<dim3(32, 6, 3), 256, 0, stream>>>(
      ctx, 768, wob, 768, part, 3145728, 768, nullptr, nullptr, 768, 768, 3);
  reduce_k<<<3072, 256, 0, stream>>>(part, x, bo, x1);

  ln_k<<<4096, 256, 0, stream>>>(x1, g2, b2n, h2);

  gemm_k<EPI_GELU><<<dim3(32, 24, 1), 256, 0, stream>>>(
      h2, 768, w1b, 768, ffn1, 0, 3072, b1f, nullptr, 3072, 768, 1);

  gemm_k<EPI_PARTIAL><<<dim3(32, 6, 3), 256, 0, stream>>>(
      ffn1, 3072, w2b, 3072, part, 3145728, 768, nullptr, nullptr, 768, 3072, 3);
  reduce_k<<<3072, 256, 0, stream>>>(part, x1, b2f, outp);
}